// Round 5
// baseline (424.481 us; speedup 1.0000x reference)
//
#include <hip/hip_runtime.h>
#include <hip/hip_bf16.h>
#include <cstdint>

// LSTMCell B=8192, IN=H=1024, fp32 in/out.
// R5: ZERO-LDS GEMM. R4 showed vmcnt is a single FIFO counter: the
// compiler's vmcnt(0) before every __syncthreads (needed by global_load_lds)
// drains B register prefetches too -- the barrier itself is the plateau.
// Fix: pre-pack BOTH operands in exact MFMA fragment order:
//   Af [mg][kt] chunk of 1KB: lane=(k>>3&1)*32+(m&31), elems k&7
//   Bt2[jg][kt][gate] chunk of 1KB: lane=(k>>3&1)*32+(j&31), elems k&7
// K-loop = pure global_load_dwordx4 (L2-resident) + MFMA, no LDS, no
// barriers, explicit register double-buffer. Compiler emits fine-grained
// vmcnt(N) with ~8 MFMA (~500 cyc) between prefetch and use.

#define B_DIM 8192
#define H_DIM 1024
#define K2    2048   // IN + H
#define N4    4096   // 4 * H
#define NKT   (K2 / 16)   // 128 k-tiles

typedef __bf16 bf16x8 __attribute__((ext_vector_type(8)));
typedef float  f32x16 __attribute__((ext_vector_type(16)));

__device__ __forceinline__ float sigm(float x) {
  return 1.0f / (1.0f + __expf(-x));
}
__device__ __forceinline__ float tanh_fast(float x) {
  return 2.0f / (1.0f + __expf(-2.0f * x)) - 1.0f;
}

// ---- cast A = [x|h] row r -> fragment-packed Af[mg=r>>5][kt][lane]x8 ----
// lane = (k>>3 & 1)*32 + (r&31), elem = k&7.
__global__ void cast_a(const float* __restrict__ x, const float* __restrict__ h,
                       __bf16* __restrict__ Af) {
  int r = blockIdx.x;
  int t = threadIdx.x;
  int k = t << 3;
  const float* src = (k < H_DIM) ? (x + (size_t)r * H_DIM + k)
                                 : (h + (size_t)r * H_DIM + (k - H_DIM));
  float4 v0 = *(const float4*)src;
  float4 v1 = *(const float4*)(src + 4);
  bf16x8 o;
  o[0] = (__bf16)v0.x; o[1] = (__bf16)v0.y; o[2] = (__bf16)v0.z; o[3] = (__bf16)v0.w;
  o[4] = (__bf16)v1.x; o[5] = (__bf16)v1.y; o[6] = (__bf16)v1.z; o[7] = (__bf16)v1.w;
  // mg = r>>5, kt = t>>1, h8 = t&1
  size_t addr = (((size_t)(r >> 5) * NKT + (t >> 1)) * 512) +
                ((size_t)((t & 1) * 32 + (r & 31))) * 8;
  *(bf16x8*)&Af[addr] = o;
}

// ------- pack weights into MFMA-B-fragment order Bt2[jg][kt][gate][lane]x8 -------
// (unchanged from R4; validated absmax 0.031)
__global__ void cast_w(const float* __restrict__ Wii, const float* __restrict__ Wif,
                       const float* __restrict__ Wig, const float* __restrict__ Wio,
                       const float* __restrict__ Whi, const float* __restrict__ Whf,
                       const float* __restrict__ Whg, const float* __restrict__ Who,
                       __bf16* __restrict__ Bt2) {
  __shared__ float tile[64][33];
  int k0 = blockIdx.x * 64;
  int jg = blockIdx.y;
  int j0 = jg * 32;
  int gate = blockIdx.z;
  const float* Wi[4] = {Wii, Wif, Wig, Wio};
  const float* Wh[4] = {Whi, Whf, Whg, Who};
  const float* W = (k0 < H_DIM) ? Wi[gate] : Wh[gate];
  int kb = (k0 < H_DIM) ? k0 : (k0 - H_DIM);

  int col = threadIdx.x & 31;
  int rr  = threadIdx.x >> 5;
#pragma unroll
  for (int p = 0; p < 8; ++p)
    tile[p * 8 + rr][col] = W[(size_t)(kb + p * 8 + rr) * H_DIM + j0 + col];
  __syncthreads();

  int jj = threadIdx.x & 31;
  int kq = threadIdx.x >> 5;          // kt_local = kq>>1, h8 = kq&1
  int kt = (k0 >> 4) + (kq >> 1);
  int h8 = kq & 1;
  bf16x8 o;
#pragma unroll
  for (int e = 0; e < 8; ++e) o[e] = (__bf16)tile[kq * 8 + e][jj];
  size_t chunk = ((size_t)jg * NKT + kt) * 4 + gate;
  *(bf16x8*)&Bt2[chunk * 512 + (h8 * 32 + jj) * 8] = o;
}

// ---------------- fused GEMM + LSTM gate epilogue (no LDS, no barriers) ----------------
// grid: (8192/128, 4096/256) = (64, 16), block 256 (4 waves)
// wave tile 64x128: 2 m-tiles x 4 gate-tiles of 32x32x16 bf16 MFMA.
__global__ __launch_bounds__(256, 2) void lstm_gemm(
    const __bf16* __restrict__ Af,   // fragment-packed activations
    const __bf16* __restrict__ Bt2,  // fragment-packed weights
    const float* __restrict__ c,
    const float* __restrict__ bi, const float* __restrict__ bf_,
    const float* __restrict__ bg, const float* __restrict__ bo,
    float* __restrict__ out_c, float* __restrict__ out_h) {
  const int tid  = threadIdx.x;
  const int wave = tid >> 6;
  const int lane = tid & 63;
  const int wm   = wave >> 1;              // 0..1 : m pair
  const int wn   = wave & 1;               // 0..1 : j-group
  const int jg   = blockIdx.y * 2 + wn;
  const int mg0  = blockIdx.x * 4 + wm * 2;

  f32x16 acc[2][4] = {};

  const __bf16* pA0 = Af  + ((size_t)(mg0 + 0) * NKT) * 512 + lane * 8;
  const __bf16* pA1 = Af  + ((size_t)(mg0 + 1) * NKT) * 512 + lane * 8;
  const __bf16* pB  = Bt2 + ((size_t)jg * NKT * 4) * 512 + lane * 8;

  bf16x8 a0[2], b0[4], a1[2], b1[4];
  a0[0] = *(const bf16x8*)(pA0);
  a0[1] = *(const bf16x8*)(pA1);
#pragma unroll
  for (int g = 0; g < 4; ++g) b0[g] = *(const bf16x8*)(pB + g * 512);

#pragma unroll 2
  for (int kt = 0; kt < NKT - 1; ++kt) {
    // prefetch kt+1 (pure register loads; no barrier will ever drain them)
    a1[0] = *(const bf16x8*)(pA0 + (size_t)(kt + 1) * 512);
    a1[1] = *(const bf16x8*)(pA1 + (size_t)(kt + 1) * 512);
#pragma unroll
    for (int g = 0; g < 4; ++g)
      b1[g] = *(const bf16x8*)(pB + ((size_t)(kt + 1) * 4 + g) * 512);

#pragma unroll
    for (int tm = 0; tm < 2; ++tm)
#pragma unroll
      for (int g = 0; g < 4; ++g)
        acc[tm][g] = __builtin_amdgcn_mfma_f32_32x32x16_bf16(
            a0[tm], b0[g], acc[tm][g], 0, 0, 0);

    a0[0] = a1[0]; a0[1] = a1[1];
#pragma unroll
    for (int g = 0; g < 4; ++g) b0[g] = b1[g];
  }
  // last k-tile
#pragma unroll
  for (int tm = 0; tm < 2; ++tm)
#pragma unroll
    for (int g = 0; g < 4; ++g)
      acc[tm][g] = __builtin_amdgcn_mfma_f32_32x32x16_bf16(
          a0[tm], b0[g], acc[tm][g], 0, 0, 0);

  // epilogue: lane-local gates (gate == second acc index); validated R3/R4.
  const int l31 = lane & 31;
  const int h8  = lane >> 5;
  const int j = jg * 32 + l31;
  const float vbi = bi[j], vbf = bf_[j], vbg = bg[j], vbo = bo[j];

#pragma unroll
  for (int tm = 0; tm < 2; ++tm) {
#pragma unroll
    for (int r = 0; r < 16; ++r) {
      int row = (mg0 + tm) * 32 + 4 * h8 + (r & 3) + 8 * (r >> 2);
      float gi = sigm(acc[tm][0][r] + vbi);
      float gf = sigm(acc[tm][1][r] + vbf);
      float gg = tanh_fast(acc[tm][2][r] + vbg);
      float go = sigm(acc[tm][3][r] + vbo);
      size_t idx = (size_t)row * H_DIM + j;
      float cv = c[idx];
      float nc = gf * cv + gi * gg;
      float nh = go * tanh_fast(nc);
      out_c[idx] = nc;
      out_h[idx] = nh;
    }
  }
}

extern "C" void kernel_launch(void* const* d_in, const int* in_sizes, int n_in,
                              void* d_out, int out_size, void* d_ws, size_t ws_size,
                              hipStream_t stream) {
  const float* x   = (const float*)d_in[0];
  const float* c   = (const float*)d_in[1];
  const float* h   = (const float*)d_in[2];
  const float* Wii = (const float*)d_in[3];
  const float* Wif = (const float*)d_in[4];
  const float* Wig = (const float*)d_in[5];
  const float* Wio = (const float*)d_in[6];
  const float* Whi = (const float*)d_in[7];
  const float* Whf = (const float*)d_in[8];
  const float* Whg = (const float*)d_in[9];
  const float* Who = (const float*)d_in[10];
  const float* bi  = (const float*)d_in[11];
  const float* bf_ = (const float*)d_in[12];
  const float* bg  = (const float*)d_in[13];
  const float* bo  = (const float*)d_in[14];

  __bf16* Af  = (__bf16*)d_ws;                                   // 32 MiB
  __bf16* Bt2 = (__bf16*)((char*)d_ws + (size_t)B_DIM * K2 * 2); // 16 MiB

  float* out_c = (float*)d_out;
  float* out_h = out_c + (size_t)B_DIM * H_DIM;

  cast_a<<<B_DIM, 256, 0, stream>>>(x, h, Af);
  dim3 gw(K2 / 64, H_DIM / 32, 4);
  cast_w<<<gw, 256, 0, stream>>>(Wii, Wif, Wig, Wio, Whi, Whf, Whg, Who, Bt2);
  dim3 gg(B_DIM / 128, N4 / 256);
  lstm_gemm<<<gg, 256, 0, stream>>>(Af, Bt2, c, bi, bf_, bg, bo, out_c, out_h);
}